// Round 1
// baseline (202.869 us; speedup 1.0000x reference)
//
#include <hip/hip_runtime.h>
#include <stdint.h>

// Problem constants: B=2, N=2048, D=1024, HEADS=16, DH=64, SCALE=0.125
using bf16x8 = __attribute__((ext_vector_type(8))) short;
using f32x4  = __attribute__((ext_vector_type(4))) float;
using s16x4  = __attribute__((ext_vector_type(4))) short;

__device__ __forceinline__ short f2bf(float f) {
    union { float f; uint32_t u; } v; v.f = f;
    uint32_t u = v.u;
    uint32_t r = (u + 0x7fffu + ((u >> 16) & 1u)) >> 16;  // RNE
    return (short)r;
}

// async global->LDS, 16B per lane; LDS dest = wave-uniform base + lane*16
__device__ __forceinline__ void gload_lds16(const void* g, void* l) {
    __builtin_amdgcn_global_load_lds(
        reinterpret_cast<const uint32_t __attribute__((address_space(1)))*>(
            reinterpret_cast<uintptr_t>(g)),
        reinterpret_cast<uint32_t __attribute__((address_space(3)))*>(
            reinterpret_cast<uintptr_t>(l)),
        16, 0, 0);
}

// ---------------- fused fp32 -> bf16 conversion (x + 4 weights) -------------
__global__ __launch_bounds__(256) void cvt_all(
    const float* __restrict__ x, const float* __restrict__ wq,
    const float* __restrict__ wk, const float* __restrict__ wv,
    const float* __restrict__ wo,
    short* __restrict__ xb, short* __restrict__ wqb, short* __restrict__ wkb,
    short* __restrict__ wvb, short* __restrict__ wob)
{
    int i = blockIdx.x * 256 + threadIdx.x;   // float4 index, total 2097152
    const float* src; short* dst; int off;
    if      (i < 1048576) { src = x;  dst = xb;  off = i; }
    else if (i < 1310720) { src = wq; dst = wqb; off = i - 1048576; }
    else if (i < 1572864) { src = wk; dst = wkb; off = i - 1310720; }
    else if (i < 1835008) { src = wv; dst = wvb; off = i - 1572864; }
    else                  { src = wo; dst = wob; off = i - 1835008; }
    float4 f = ((const float4*)src)[off];
    s16x4 r; r[0] = f2bf(f.x); r[1] = f2bf(f.y); r[2] = f2bf(f.z); r[3] = f2bf(f.w);
    ((s16x4*)dst)[off] = r;
}

// ---------------- GEMM: C = A(MxK) * B(NxK)^T, bf16, 128x128 tile -----------
// IS_OUT=false: z=0 -> qb (scaled 0.125, [B,H,N,dh]), z=1 -> kb ([B,H,N,dh]),
//               z=2 -> vtb ([B,H,dh,N]).  IS_OUT=true: fp32 out + bias.
template <bool IS_OUT>
__global__ __launch_bounds__(256) void gemm_bt(
    const short* __restrict__ A,
    const short* __restrict__ Bq, const short* __restrict__ Bk,
    const short* __restrict__ Bv,
    short* __restrict__ qb, short* __restrict__ kb, short* __restrict__ vtb,
    float* __restrict__ outp, const float* __restrict__ bias)
{
    __shared__ short As[128 * 64];
    __shared__ short Bs[128 * 64];
    const int tid  = threadIdx.x;
    const int wave = tid >> 6, lane = tid & 63;
    const int lo = lane & 15, hi = lane >> 4;
    const int m_base = blockIdx.y * 128;
    const int n_base = blockIdx.x * 128;
    const int z = blockIdx.z;
    const short* Bw = IS_OUT ? Bq : (z == 0 ? Bq : (z == 1 ? Bk : Bv));
    const int wr = wave >> 1, wc = wave & 1;

    f32x4 acc[4][4];
#pragma unroll
    for (int i = 0; i < 4; ++i)
#pragma unroll
        for (int j = 0; j < 4; ++j) acc[i][j] = (f32x4){0.f, 0.f, 0.f, 0.f};

    const int srow = wave * 32 + (lane >> 3);   // staged row (this wave, c=0)
    const int se   = (lane & 7) * 8;            // elem offset within 64-col row
    const short* Ag = A  + (size_t)(m_base + srow) * 1024 + se;
    const short* Bg = Bw + (size_t)(n_base + srow) * 1024 + se;

    for (int k0 = 0; k0 < 1024; k0 += 64) {
#pragma unroll
        for (int c = 0; c < 4; ++c) {
            gload_lds16(Ag + (size_t)c * 8 * 1024 + k0, &As[(wave * 32 + c * 8) * 64]);
            gload_lds16(Bg + (size_t)c * 8 * 1024 + k0, &Bs[(wave * 32 + c * 8) * 64]);
        }
        __syncthreads();
#pragma unroll
        for (int ks = 0; ks < 2; ++ks) {
            bf16x8 av[4], bv[4];
#pragma unroll
            for (int i = 0; i < 4; ++i)
                av[i] = *(const bf16x8*)&As[(wr * 64 + i * 16 + lo) * 64 + ks * 32 + hi * 8];
#pragma unroll
            for (int i = 0; i < 4; ++i)
                bv[i] = *(const bf16x8*)&Bs[(wc * 64 + i * 16 + lo) * 64 + ks * 32 + hi * 8];
#pragma unroll
            for (int mi = 0; mi < 4; ++mi)
#pragma unroll
                for (int ni = 0; ni < 4; ++ni)
                    acc[mi][ni] = __builtin_amdgcn_mfma_f32_16x16x32_bf16(
                        av[mi], bv[ni], acc[mi][ni], 0, 0, 0);
        }
        __syncthreads();
    }

    // epilogue: C frag (m = .. + hi*4 + i, n = .. + lo)
#pragma unroll
    for (int mi = 0; mi < 4; ++mi) {
#pragma unroll
        for (int ni = 0; ni < 4; ++ni) {
            const int n = n_base + wc * 64 + ni * 16 + lo;
            if (IS_OUT) {
                const float bsv = bias[n];
#pragma unroll
                for (int i = 0; i < 4; ++i) {
                    const int m = m_base + wr * 64 + mi * 16 + hi * 4 + i;
                    outp[(size_t)m * 1024 + n] = acc[mi][ni][i] + bsv;
                }
            } else {
                const int h = n >> 6, d = n & 63;
                if (z == 2) {   // V transposed: [B,H,dh,N], pack 4 seq rows
                    const int m0 = m_base + wr * 64 + mi * 16 + hi * 4;
                    const int b = m0 >> 11, ns = m0 & 2047;
                    s16x4 pk;
#pragma unroll
                    for (int i = 0; i < 4; ++i) pk[i] = f2bf(acc[mi][ni][i]);
                    *(s16x4*)&vtb[(((size_t)b * 16 + h) * 64 + d) * 2048 + ns] = pk;
                } else {
                    short* dstp = (z == 0) ? qb : kb;
                    const float scl = (z == 0) ? 0.125f : 1.0f;
#pragma unroll
                    for (int i = 0; i < 4; ++i) {
                        const int m = m_base + wr * 64 + mi * 16 + hi * 4 + i;
                        const int b = m >> 11, ns = m & 2047;
                        dstp[(((size_t)b * 16 + h) * 2048 + ns) * 64 + d] =
                            f2bf(acc[mi][ni][i] * scl);
                    }
                }
            }
        }
    }
}

// ---------------- flash attention: q[BHNd]*0.125 pre-applied ---------------
// grid (16 q-tiles, 32 bh). 4 waves x 32 q-rows. KV tile = 64.
// K_lds/V_lds XOR-swizzled (write-side: pre-swizzled global source;
// read-side: slot ^ (row&7)) to kill the 128B-row 16-way bank conflict.
__global__ __launch_bounds__(256) void attn(
    const short* __restrict__ qg, const short* __restrict__ kg,
    const short* __restrict__ vtg, short* __restrict__ ob)
{
    __shared__ short K_lds[64 * 64];
    __shared__ short V_lds[64 * 64];
    __shared__ short P_lds[4 * 32 * 64];

    const int tid  = threadIdx.x;
    const int wave = tid >> 6, lane = tid & 63;
    const int lo = lane & 15, hi = lane >> 4;
    const int bh = blockIdx.y;
    const int qw = blockIdx.x * 128 + wave * 32;

    // Q fragments in registers for the whole kernel (already * SCALE)
    bf16x8 qf[2][2];
#pragma unroll
    for (int mi = 0; mi < 2; ++mi)
#pragma unroll
        for (int ks = 0; ks < 2; ++ks)
            qf[mi][ks] = *(const bf16x8*)&qg[((size_t)bh * 2048 + qw + mi * 16 + lo) * 64 +
                                             ks * 32 + hi * 8];

    f32x4 oacc[2][4];
#pragma unroll
    for (int mi = 0; mi < 2; ++mi)
#pragma unroll
        for (int nf = 0; nf < 4; ++nf) oacc[mi][nf] = (f32x4){0.f, 0.f, 0.f, 0.f};
    float mrow[2][4], lrow[2][4];
#pragma unroll
    for (int mi = 0; mi < 2; ++mi)
#pragma unroll
        for (int i = 0; i < 4; ++i) { mrow[mi][i] = -3.0e38f; lrow[mi][i] = 0.f; }

    const int isV   = wave >> 1;          // waves 0,1 stage K; 2,3 stage V^T
    const int rbase = (wave & 1) * 32;
    char* pbase = (char*)P_lds + wave * 4096;

    for (int t = 0; t < 32; ++t) {
        const int kv0 = t * 64;
        // -------- stage K (rows=kv, cols=dh) and V^T (rows=dh, cols=kv) -----
#pragma unroll
        for (int c = 0; c < 4; ++c) {
            const int r  = rbase + c * 8 + (lane >> 3);
            const int sg = (lane & 7) ^ (r & 7);        // inverse-swizzled src slot
            if (isV == 0) {
                gload_lds16(kg + ((size_t)bh * 2048 + kv0 + r) * 64 + sg * 8,
                            &K_lds[(rbase + c * 8) * 64]);
            } else {
                gload_lds16(vtg + ((size_t)bh * 64 + r) * 2048 + kv0 + sg * 8,
                            &V_lds[(rbase + c * 8) * 64]);
            }
        }
        __syncthreads();

        // -------- S = Q K^T (frags: m=q-row, n=kv) --------------------------
        f32x4 s[2][4];
#pragma unroll
        for (int mi = 0; mi < 2; ++mi)
#pragma unroll
            for (int nf = 0; nf < 4; ++nf) s[mi][nf] = (f32x4){0.f, 0.f, 0.f, 0.f};
#pragma unroll
        for (int ks = 0; ks < 2; ++ks) {
            bf16x8 kf[4];
#pragma unroll
            for (int nf = 0; nf < 4; ++nf) {
                const int row = nf * 16 + lo;
                kf[nf] = *(const bf16x8*)((const char*)K_lds + row * 128 +
                                          (((ks * 4 + hi) ^ (lo & 7)) << 4));
            }
#pragma unroll
            for (int mi = 0; mi < 2; ++mi)
#pragma unroll
                for (int nf = 0; nf < 4; ++nf)
                    s[mi][nf] = __builtin_amdgcn_mfma_f32_16x16x32_bf16(
                        qf[mi][ks], kf[nf], s[mi][nf], 0, 0, 0);
        }

        // -------- online softmax (row r = mi*16 + hi*4 + i, col = nf*16+lo) -
#pragma unroll
        for (int mi = 0; mi < 2; ++mi) {
#pragma unroll
            for (int i = 0; i < 4; ++i) {
                float tm = fmaxf(fmaxf(s[mi][0][i], s[mi][1][i]),
                                 fmaxf(s[mi][2][i], s[mi][3][i]));
#pragma unroll
                for (int off = 1; off < 16; off <<= 1)
                    tm = fmaxf(tm, __shfl_xor(tm, off));
                const float mold = mrow[mi][i];
                const float mnew = fmaxf(mold, tm);
                const float alpha = __expf(mold - mnew);
                mrow[mi][i] = mnew;
                float ts = 0.f;
#pragma unroll
                for (int nf = 0; nf < 4; ++nf) {
                    const float p = __expf(s[mi][nf][i] - mnew);
                    s[mi][nf][i] = p;
                    ts += p;
                }
#pragma unroll
                for (int off = 1; off < 16; off <<= 1)
                    ts += __shfl_xor(ts, off);
                lrow[mi][i] = lrow[mi][i] * alpha + ts;
#pragma unroll
                for (int nf = 0; nf < 4; ++nf) oacc[mi][nf][i] *= alpha;
            }
        }

        // -------- P -> LDS (bf16, XOR-swizzled), then PV ---------------------
#pragma unroll
        for (int mi = 0; mi < 2; ++mi)
#pragma unroll
            for (int nf = 0; nf < 4; ++nf) {
                const int slot = nf * 2 + (lo >> 3);
#pragma unroll
                for (int i = 0; i < 4; ++i) {
                    const int row = mi * 16 + hi * 4 + i;
                    *(short*)(pbase + row * 128 + ((slot ^ (row & 7)) << 4) +
                              ((lo & 7) << 1)) = f2bf(s[mi][nf][i]);
                }
            }
        asm volatile("s_waitcnt lgkmcnt(0)" ::: "memory");

#pragma unroll
        for (int ks = 0; ks < 2; ++ks) {
            bf16x8 pa[2], vf[4];
#pragma unroll
            for (int mi = 0; mi < 2; ++mi) {
                const int row = mi * 16 + lo;
                pa[mi] = *(const bf16x8*)(pbase + row * 128 +
                                          (((ks * 4 + hi) ^ (lo & 7)) << 4));
            }
#pragma unroll
            for (int nf = 0; nf < 4; ++nf) {
                const int row = nf * 16 + lo;
                vf[nf] = *(const bf16x8*)((const char*)V_lds + row * 128 +
                                          (((ks * 4 + hi) ^ (lo & 7)) << 4));
            }
#pragma unroll
            for (int mi = 0; mi < 2; ++mi)
#pragma unroll
                for (int nf = 0; nf < 4; ++nf)
                    oacc[mi][nf] = __builtin_amdgcn_mfma_f32_16x16x32_bf16(
                        pa[mi], vf[nf], oacc[mi][nf], 0, 0, 0);
        }
        __syncthreads();
    }

    // -------- epilogue: o /= l, write [B, N, H*dh] bf16 ----------------------
    const int b = bh >> 4, h = bh & 15;
#pragma unroll
    for (int mi = 0; mi < 2; ++mi)
#pragma unroll
        for (int nf = 0; nf < 4; ++nf)
#pragma unroll
            for (int i = 0; i < 4; ++i) {
                const int qrow = qw + mi * 16 + hi * 4 + i;
                ob[((size_t)b * 2048 + qrow) * 1024 + h * 64 + nf * 16 + lo] =
                    f2bf(oacc[mi][nf][i] / lrow[mi][i]);
            }
}

// ---------------------------------------------------------------------------
extern "C" void kernel_launch(void* const* d_in, const int* in_sizes, int n_in,
                              void* d_out, int out_size, void* d_ws, size_t ws_size,
                              hipStream_t stream) {
    const float* x   = (const float*)d_in[0];
    const float* Wq  = (const float*)d_in[1];
    const float* Wk  = (const float*)d_in[2];
    const float* Wv  = (const float*)d_in[3];
    const float* Wo  = (const float*)d_in[4];
    const float* bo  = (const float*)d_in[5];
    float* outp = (float*)d_out;

    char* ws = (char*)d_ws;
    short* xb  = (short*)(ws);                     // 8 MB  (4096x1024 bf16)
    short* qb  = (short*)(ws + (8u  << 20));       // 8 MB  [B,H,N,dh]
    short* kb  = (short*)(ws + (16u << 20));       // 8 MB  [B,H,N,dh]
    short* vtb = (short*)(ws + (24u << 20));       // 8 MB  [B,H,dh,N]
    short* ob  = (short*)(ws + (32u << 20));       // 8 MB  (4096x1024 bf16)
    short* wqb = (short*)(ws + (40u << 20));       // 2 MB each
    short* wkb = (short*)(ws + (42u << 20));
    short* wvb = (short*)(ws + (44u << 20));
    short* wob = (short*)(ws + (46u << 20));

    cvt_all<<<8192, 256, 0, stream>>>(x, Wq, Wk, Wv, Wo, xb, wqb, wkb, wvb, wob);
    gemm_bt<false><<<dim3(8, 32, 3), 256, 0, stream>>>(
        xb, wqb, wkb, wvb, qb, kb, vtb, nullptr, nullptr);
    attn<<<dim3(16, 32), 256, 0, stream>>>(qb, kb, vtb, ob);
    gemm_bt<true><<<dim3(8, 32, 1), 256, 0, stream>>>(
        ob, wob, nullptr, nullptr, nullptr, nullptr, nullptr, outp, bo);
}

// Round 3
// 154.122 us; speedup vs baseline: 1.3163x; 1.3163x over previous
//
#include <hip/hip_runtime.h>
#include <stdint.h>

// Problem constants: B=2, N=2048, D=1024, HEADS=16, DH=64, SCALE=0.125
using bf16x8 = __attribute__((ext_vector_type(8))) short;
using f32x4  = __attribute__((ext_vector_type(4))) float;
using s16x4  = __attribute__((ext_vector_type(4))) short;

__device__ __forceinline__ short f2bf(float f) {
    union { float f; uint32_t u; } v; v.f = f;
    uint32_t u = v.u;
    uint32_t r = (u + 0x7fffu + ((u >> 16) & 1u)) >> 16;  // RNE
    return (short)r;
}

__device__ __forceinline__ uint32_t cvtpk_bf16(float a, float b) {
    uint32_t r;
    asm("v_cvt_pk_bf16_f32 %0, %1, %2" : "=v"(r) : "v"(a), "v"(b));
    return r;  // lo = bf16(a), hi = bf16(b)
}

// async global->LDS, 16B per lane; LDS dest = wave-uniform base + lane*16
__device__ __forceinline__ void gload_lds16(const void* g, void* l) {
    __builtin_amdgcn_global_load_lds(
        reinterpret_cast<const uint32_t __attribute__((address_space(1)))*>(
            reinterpret_cast<uintptr_t>(g)),
        reinterpret_cast<uint32_t __attribute__((address_space(3)))*>(
            reinterpret_cast<uintptr_t>(l)),
        16, 0, 0);
}

// ---------------- fused fp32 -> bf16 conversion (x + 4 weights) -------------
__global__ __launch_bounds__(256) void cvt_all(
    const float* __restrict__ x, const float* __restrict__ wq,
    const float* __restrict__ wk, const float* __restrict__ wv,
    const float* __restrict__ wo,
    short* __restrict__ xb, short* __restrict__ wqb, short* __restrict__ wkb,
    short* __restrict__ wvb, short* __restrict__ wob)
{
    int i = blockIdx.x * 256 + threadIdx.x;   // float4 index, total 2097152
    const float* src; short* dst; int off;
    if      (i < 1048576) { src = x;  dst = xb;  off = i; }
    else if (i < 1310720) { src = wq; dst = wqb; off = i - 1048576; }
    else if (i < 1572864) { src = wk; dst = wkb; off = i - 1310720; }
    else if (i < 1835008) { src = wv; dst = wvb; off = i - 1572864; }
    else                  { src = wo; dst = wob; off = i - 1835008; }
    float4 f = ((const float4*)src)[off];
    s16x4 r; r[0] = f2bf(f.x); r[1] = f2bf(f.y); r[2] = f2bf(f.z); r[3] = f2bf(f.w);
    ((s16x4*)dst)[off] = r;
}

// ---------------- GEMM: C = A(MxK) * B(NxK)^T, bf16, 128x128 tile -----------
// IS_OUT=false: z=0 -> qb (scaled 0.125*log2e, [B,H,N,dh]), z=1 -> kb,
//               z=2 -> vtb ([B,H,dh,N]).  IS_OUT=true: fp32 out + bias.
template <bool IS_OUT>
__global__ __launch_bounds__(256) void gemm_bt(
    const short* __restrict__ A,
    const short* __restrict__ Bq, const short* __restrict__ Bk,
    const short* __restrict__ Bv,
    short* __restrict__ qb, short* __restrict__ kb, short* __restrict__ vtb,
    float* __restrict__ outp, const float* __restrict__ bias)
{
    __shared__ short As[128 * 64];
    __shared__ short Bs[128 * 64];
    const int tid  = threadIdx.x;
    const int wave = tid >> 6, lane = tid & 63;
    const int lo = lane & 15, hi = lane >> 4;
    const int m_base = blockIdx.y * 128;
    const int n_base = blockIdx.x * 128;
    const int z = blockIdx.z;
    const short* Bw = IS_OUT ? Bq : (z == 0 ? Bq : (z == 1 ? Bk : Bv));
    const int wr = wave >> 1, wc = wave & 1;

    f32x4 acc[4][4];
#pragma unroll
    for (int i = 0; i < 4; ++i)
#pragma unroll
        for (int j = 0; j < 4; ++j) acc[i][j] = (f32x4){0.f, 0.f, 0.f, 0.f};

    const int srow = wave * 32 + (lane >> 3);   // staged row (this wave, c=0)
    const int se   = (lane & 7) * 8;            // elem offset within 64-col row
    const short* Ag = A  + (size_t)(m_base + srow) * 1024 + se;
    const short* Bg = Bw + (size_t)(n_base + srow) * 1024 + se;

    for (int k0 = 0; k0 < 1024; k0 += 64) {
#pragma unroll
        for (int c = 0; c < 4; ++c) {
            gload_lds16(Ag + (size_t)c * 8 * 1024 + k0, &As[(wave * 32 + c * 8) * 64]);
            gload_lds16(Bg + (size_t)c * 8 * 1024 + k0, &Bs[(wave * 32 + c * 8) * 64]);
        }
        __syncthreads();
#pragma unroll
        for (int ks = 0; ks < 2; ++ks) {
            bf16x8 av[4], bv[4];
#pragma unroll
            for (int i = 0; i < 4; ++i)
                av[i] = *(const bf16x8*)&As[(wr * 64 + i * 16 + lo) * 64 + ks * 32 + hi * 8];
#pragma unroll
            for (int i = 0; i < 4; ++i)
                bv[i] = *(const bf16x8*)&Bs[(wc * 64 + i * 16 + lo) * 64 + ks * 32 + hi * 8];
#pragma unroll
            for (int mi = 0; mi < 4; ++mi)
#pragma unroll
                for (int ni = 0; ni < 4; ++ni)
                    acc[mi][ni] = __builtin_amdgcn_mfma_f32_16x16x32_bf16(
                        av[mi], bv[ni], acc[mi][ni], 0, 0, 0);
        }
        __syncthreads();
    }

    // epilogue: C frag (m = .. + hi*4 + i, n = .. + lo)
#pragma unroll
    for (int mi = 0; mi < 4; ++mi) {
#pragma unroll
        for (int ni = 0; ni < 4; ++ni) {
            const int n = n_base + wc * 64 + ni * 16 + lo;
            if (IS_OUT) {
                const float bsv = bias[n];
#pragma unroll
                for (int i = 0; i < 4; ++i) {
                    const int m = m_base + wr * 64 + mi * 16 + hi * 4 + i;
                    outp[(size_t)m * 1024 + n] = acc[mi][ni][i] + bsv;
                }
            } else {
                const int h = n >> 6, d = n & 63;
                if (z == 2) {   // V transposed: [B,H,dh,N], pack 4 seq rows
                    const int m0 = m_base + wr * 64 + mi * 16 + hi * 4;
                    const int b = m0 >> 11, ns = m0 & 2047;
                    s16x4 pk;
#pragma unroll
                    for (int i = 0; i < 4; ++i) pk[i] = f2bf(acc[mi][ni][i]);
                    *(s16x4*)&vtb[(((size_t)b * 16 + h) * 64 + d) * 2048 + ns] = pk;
                } else {
                    short* dstp = (z == 0) ? qb : kb;
                    // Q scale folded with log2(e) so softmax uses exp2 directly
                    const float scl = (z == 0) ? 0.18033688011112042f : 1.0f;
#pragma unroll
                    for (int i = 0; i < 4; ++i) {
                        const int m = m_base + wr * 64 + mi * 16 + hi * 4 + i;
                        const int b = m >> 11, ns = m & 2047;
                        dstp[(((size_t)b * 16 + h) * 2048 + ns) * 64 + d] =
                            f2bf(acc[mi][ni][i] * scl);
                    }
                }
            }
        }
    }
}

// ---------------- flash attention (swapped QK^T, lane-local softmax) --------
// grid (16 q-tiles, 32 bh). 4 waves x 32 q-rows. KV tile = 64, double-buffered.
// Q pre-scaled by 0.125*log2e -> exp2 softmax.
__global__ __launch_bounds__(256) void attn(
    const short* __restrict__ qg, const short* __restrict__ kg,
    const short* __restrict__ vtg, short* __restrict__ ob)
{
    __shared__ short K_lds[2][64 * 64];
    __shared__ short V_lds[2][64 * 64];
    __shared__ short P_lds[4 * 32 * 64];

    const int tid  = threadIdx.x;
    const int wave = tid >> 6, lane = tid & 63;
    const int lo = lane & 15, hi = lane >> 4;
    const int bh = blockIdx.y;
    const int qw = blockIdx.x * 128 + wave * 32;

    // Q fragments in registers for the whole kernel (already * SCALE*log2e)
    bf16x8 qf[2][2];
#pragma unroll
    for (int nf = 0; nf < 2; ++nf)
#pragma unroll
        for (int ks = 0; ks < 2; ++ks)
            qf[nf][ks] = *(const bf16x8*)&qg[((size_t)bh * 2048 + qw + nf * 16 + lo) * 64 +
                                             ks * 32 + hi * 8];

    f32x4 oacc[2][4];
#pragma unroll
    for (int mi = 0; mi < 2; ++mi)
#pragma unroll
        for (int nf = 0; nf < 4; ++nf) oacc[mi][nf] = (f32x4){0.f, 0.f, 0.f, 0.f};
    float mrow[2] = {-1e30f, -1e30f};   // running max (log2 domain), q=nf*16+lo
    float lrow[2] = {0.f, 0.f};         // running sum

    const int stV   = wave >> 1;          // waves 0,1 stage K; 2,3 stage V^T
    const int rbase = (wave & 1) * 32;
    char* pbase = (char*)P_lds + wave * 4096;
    const short* kgb = kg  + (size_t)bh * 2048 * 64;
    const short* vgb = vtg + (size_t)bh * 64 * 2048;

    auto STAGE = [&](int buf, int t) {
        const int kv0 = t * 64;
#pragma unroll
        for (int c = 0; c < 4; ++c) {
            const int r  = rbase + c * 8 + (lane >> 3);
            const int sg = (lane & 7) ^ (r & 7);        // inverse-swizzled src slot
            if (stV == 0)
                gload_lds16(kgb + (size_t)(kv0 + r) * 64 + sg * 8,
                            &K_lds[buf][(rbase + c * 8) * 64]);
            else
                gload_lds16(vgb + (size_t)r * 2048 + kv0 + sg * 8,
                            &V_lds[buf][(rbase + c * 8) * 64]);
        }
    };

    STAGE(0, 0);

    for (int t = 0; t < 32; ++t) {
        const int cur = t & 1;
        if (t < 31) {
            STAGE(cur ^ 1, t + 1);                       // next tile in flight
            asm volatile("s_waitcnt vmcnt(4)" ::: "memory");  // t's 4 loads done
        } else {
            asm volatile("s_waitcnt vmcnt(0)" ::: "memory");
        }
        __builtin_amdgcn_s_barrier();

        // -------- S^T = K Q^T (row=kv, col=q): lane-local P rows ------------
        f32x4 st[4][2];
#pragma unroll
        for (int mi = 0; mi < 4; ++mi)
#pragma unroll
            for (int nf = 0; nf < 2; ++nf) st[mi][nf] = (f32x4){0.f, 0.f, 0.f, 0.f};
#pragma unroll
        for (int ks = 0; ks < 2; ++ks) {
            bf16x8 kf[4];
#pragma unroll
            for (int mi = 0; mi < 4; ++mi) {
                const int row = mi * 16 + lo;
                kf[mi] = *(const bf16x8*)((const char*)K_lds[cur] + row * 128 +
                                          (((ks * 4 + hi) ^ (lo & 7)) << 4));
            }
#pragma unroll
            for (int mi = 0; mi < 4; ++mi)
#pragma unroll
                for (int nf = 0; nf < 2; ++nf)
                    st[mi][nf] = __builtin_amdgcn_mfma_f32_16x16x32_bf16(
                        kf[mi], qf[nf][ks], st[mi][nf], 0, 0, 0);
        }

        // -------- online softmax, col-layout (q = nf*16+lo per lane) --------
        float tm[2];
#pragma unroll
        for (int nf = 0; nf < 2; ++nf) {
            float a0 = fmaxf(fmaxf(st[0][nf][0], st[0][nf][1]),
                             fmaxf(st[0][nf][2], st[0][nf][3]));
            float a1 = fmaxf(fmaxf(st[1][nf][0], st[1][nf][1]),
                             fmaxf(st[1][nf][2], st[1][nf][3]));
            float a2 = fmaxf(fmaxf(st[2][nf][0], st[2][nf][1]),
                             fmaxf(st[2][nf][2], st[2][nf][3]));
            float a3 = fmaxf(fmaxf(st[3][nf][0], st[3][nf][1]),
                             fmaxf(st[3][nf][2], st[3][nf][3]));
            float m4 = fmaxf(fmaxf(a0, a1), fmaxf(a2, a3));
            m4 = fmaxf(m4, __shfl_xor(m4, 16));
            m4 = fmaxf(m4, __shfl_xor(m4, 32));
            tm[nf] = m4;
        }
        // defer-max (T13): skip rescale unless some row grew past THR=8
        const int keep = (tm[0] <= mrow[0] + 8.f) && (tm[1] <= mrow[1] + 8.f);
        if (!__all(keep)) {
            float alpha[2];
#pragma unroll
            for (int nf = 0; nf < 2; ++nf) {
                const float mn = fmaxf(mrow[nf], tm[nf]);
                alpha[nf] = __builtin_amdgcn_exp2f(mrow[nf] - mn);
                mrow[nf]  = mn;
                lrow[nf] *= alpha[nf];
            }
            // broadcast alpha into oacc layout (row q = mi*16 + hi*4 + i)
#pragma unroll
            for (int mi = 0; mi < 2; ++mi)
#pragma unroll
                for (int i = 0; i < 4; ++i) {
                    const float av = __shfl(alpha[mi], hi * 4 + i);
#pragma unroll
                    for (int nf = 0; nf < 4; ++nf) oacc[mi][nf][i] *= av;
                }
        }
#pragma unroll
        for (int nf = 0; nf < 2; ++nf) {
            float ts = 0.f;
#pragma unroll
            for (int mi = 0; mi < 4; ++mi)
#pragma unroll
                for (int i = 0; i < 4; ++i) {
                    const float p = __builtin_amdgcn_exp2f(st[mi][nf][i] - mrow[nf]);
                    st[mi][nf][i] = p;
                    ts += p;
                }
            ts += __shfl_xor(ts, 16);
            ts += __shfl_xor(ts, 32);
            lrow[nf] += ts;
        }

        // -------- P -> LDS (bf16 pairs, XOR-swizzled b64 writes) ------------
#pragma unroll
        for (int nf = 0; nf < 2; ++nf)
#pragma unroll
            for (int mi = 0; mi < 4; ++mi) {
                uint2 w;
                w.x = cvtpk_bf16(st[mi][nf][0], st[mi][nf][1]);
                w.y = cvtpk_bf16(st[mi][nf][2], st[mi][nf][3]);
                const int row  = nf * 16 + lo;                 // q row
                const int slot = (mi * 2 + (hi >> 1)) ^ (lo & 7);
                *(uint2*)(pbase + row * 128 + (slot << 4) + (hi & 1) * 8) = w;
            }
        asm volatile("s_waitcnt lgkmcnt(0)" ::: "memory");
        __builtin_amdgcn_sched_barrier(0);

        // -------- O += P V  (A = P rows [q][kv], B = V^T rows [dh][kv]) -----
#pragma unroll
        for (int ks = 0; ks < 2; ++ks) {
            bf16x8 pa[2], vf[4];
#pragma unroll
            for (int mi = 0; mi < 2; ++mi) {
                const int row = mi * 16 + lo;
                pa[mi] = *(const bf16x8*)(pbase + row * 128 +
                                          (((ks * 4 + hi) ^ (lo & 7)) << 4));
            }
#pragma unroll
            for (int nf = 0; nf < 4; ++nf) {
                const int row = nf * 16 + lo;
                vf[nf] = *(const bf16x8*)((const char*)V_lds[cur] + row * 128 +
                                          (((ks * 4 + hi) ^ (lo & 7)) << 4));
            }
#pragma unroll
            for (int mi = 0; mi < 2; ++mi)
#pragma unroll
                for (int nf = 0; nf < 4; ++nf)
                    oacc[mi][nf] = __builtin_amdgcn_mfma_f32_16x16x32_bf16(
                        pa[mi], vf[nf], oacc[mi][nf], 0, 0, 0);
        }
        asm volatile("s_waitcnt lgkmcnt(0)" ::: "memory");
        __builtin_amdgcn_s_barrier();
    }

    // -------- epilogue: o /= l, write [B, N, H*dh] bf16 ----------------------
    const int b = bh >> 4, h = bh & 15;
#pragma unroll
    for (int mi = 0; mi < 2; ++mi)
#pragma unroll
        for (int i = 0; i < 4; ++i) {
            const float lv = __shfl(lrow[mi], hi * 4 + i);
            const float r  = 1.0f / lv;
            const int qrow = qw + mi * 16 + hi * 4 + i;
#pragma unroll
            for (int nf = 0; nf < 4; ++nf)
                ob[((size_t)b * 2048 + qrow) * 1024 + h * 64 + nf * 16 + lo] =
                    f2bf(oacc[mi][nf][i] * r);
        }
}

// ---------------------------------------------------------------------------
extern "C" void kernel_launch(void* const* d_in, const int* in_sizes, int n_in,
                              void* d_out, int out_size, void* d_ws, size_t ws_size,
                              hipStream_t stream) {
    const float* x   = (const float*)d_in[0];
    const float* Wq  = (const float*)d_in[1];
    const float* Wk  = (const float*)d_in[2];
    const float* Wv  = (const float*)d_in[3];
    const float* Wo  = (const float*)d_in[4];
    const float* bo  = (const float*)d_in[5];
    float* outp = (float*)d_out;

    char* ws = (char*)d_ws;
    short* xb  = (short*)(ws);                     // 8 MB  (4096x1024 bf16)
    short* qb  = (short*)(ws + (8u  << 20));       // 8 MB  [B,H,N,dh]
    short* kb  = (short*)(ws + (16u << 20));       // 8 MB  [B,H,N,dh]
    short* vtb = (short*)(ws + (24u << 20));       // 8 MB  [B,H,dh,N]
    short* ob  = (short*)(ws + (32u << 20));       // 8 MB  (4096x1024 bf16)
    short* wqb = (short*)(ws + (40u << 20));       // 2 MB each
    short* wkb = (short*)(ws + (42u << 20));
    short* wvb = (short*)(ws + (44u << 20));
    short* wob = (short*)(ws + (46u << 20));

    cvt_all<<<8192, 256, 0, stream>>>(x, Wq, Wk, Wv, Wo, xb, wqb, wkb, wvb, wob);
    gemm_bt<false><<<dim3(8, 32, 3), 256, 0, stream>>>(
        xb, wqb, wkb, wvb, qb, kb, vtb, nullptr, nullptr);
    attn<<<dim3(16, 32), 256, 0, stream>>>(qb, kb, vtb, ob);
    gemm_bt<true><<<dim3(8, 32, 1), 256, 0, stream>>>(
        ob, wob, nullptr, nullptr, nullptr, nullptr, nullptr, outp, bo);
}